// Round 5
// baseline (316.459 us; speedup 1.0000x reference)
//
#include <hip/hip_runtime.h>
#include <hip/hip_bf16.h>
#include <math.h>

// ---------------- types ----------------
typedef __attribute__((ext_vector_type(4))) float   f32x4;
typedef __attribute__((ext_vector_type(8))) short   short8;
typedef __attribute__((ext_vector_type(8))) __bf16  bf16x8;

union SB8 { short8 s; bf16x8 b; };

__device__ __forceinline__ short f2bf(float f) {
  union { float f; unsigned u; } v; v.f = f;
  unsigned r = v.u + 0x7fffu + ((v.u >> 16) & 1u);   // RNE
  return (short)(r >> 16);
}

__device__ __forceinline__ short8 cvt8(f32x4 a, f32x4 b) {
  short8 r;
  r[0] = f2bf(a[0]); r[1] = f2bf(a[1]); r[2] = f2bf(a[2]); r[3] = f2bf(a[3]);
  r[4] = f2bf(b[0]); r[5] = f2bf(b[1]); r[6] = f2bf(b[2]); r[7] = f2bf(b[3]);
  return r;
}

// async global->LDS, 16B per lane; dest is wave-uniform base + lane*16
__device__ __forceinline__ void ldsload16(const short* g, short* l) {
  __builtin_amdgcn_global_load_lds(
      (const __attribute__((address_space(1))) unsigned int*)g,
      (__attribute__((address_space(3))) unsigned int*)l, 16, 0, 0);
}

// Problem constants
#define TT   2048
#define DD   1024        // K of gemm1, N of gemm2
#define HH   704
#define HSS  1408
#define EE   16
#define CAP  2048
#define CSTR 32          // counts stride in ints (128B apart -> no atomic line contention)

// bf16 segment offsets (elements) inside the big bf16 workspace buffer
#define O1  2097152ULL                    // x:  2048*1024
#define O2  13631488ULL                   // w1: 16*704*1024
#define O3  25165824ULL                   // w3
#define O4  36700160ULL                   // w2: 16*1024*704
#define O5  38141952ULL                   // ws1: 1408*1024
#define O6  39583744ULL                   // ws3
#define CVT_TOTAL 41025536ULL             // + ws2

#define W2SZ    11534336ULL               // w2 elems
#define WS1SZ   1441792ULL                // ws1 elems
#define WS1END  26607616ULL               // O3 + WS1SZ
#define CVTA_TOTAL  28049408ULL           // x + w1 + w3 + ws1 + ws3
#define CVTA_BLOCKS 3424                  // CVTA_TOTAL / 8192
#define GATE_BLOCKS 512

// ---------------- fused gate + fp32->bf16 convert (unchanged from r3) ----------------
__global__ __launch_bounds__(256)
void gate_cvt(const float* __restrict__ x,  const float* __restrict__ w1,
              const float* __restrict__ w3, const float* __restrict__ s1,
              const float* __restrict__ s3, short* __restrict__ dst,
              const float* __restrict__ gw, const float* __restrict__ gb,
              int* __restrict__ counts, int* __restrict__ tok,
              float* __restrict__ wgt, int* __restrict__ eslot)
{
  if (blockIdx.x >= GATE_BLOCKS) {
    const int tid = threadIdx.x;
    const size_t base = (size_t)(blockIdx.x - GATE_BLOCKS) * 8192;
    const float* sp[4]; short* dp[4];
    #pragma unroll
    for (int k = 0; k < 4; k++) {
      const size_t sb = base + (size_t)k * 2048;          // uniform per (block,k)
      const float* src; size_t doff;
      if      (sb < O1)     { src = x  + sb;            doff = sb; }
      else if (sb < O2)     { src = w1 + (sb - O1);     doff = sb; }
      else if (sb < O3)     { src = w3 + (sb - O2);     doff = sb; }
      else if (sb < WS1END) { src = s1 + (sb - O3);     doff = sb + W2SZ; }
      else                  { src = s3 + (sb - WS1END); doff = sb + W2SZ; }
      sp[k] = src + tid * 8;
      dp[k] = dst + doff + tid * 8;
    }
    f32x4 va[8];
    #pragma unroll
    for (int k = 0; k < 4; k++) {
      va[2 * k]     = *(const f32x4*)(sp[k]);
      va[2 * k + 1] = *(const f32x4*)(sp[k] + 4);
    }
    #pragma unroll
    for (int k = 0; k < 4; k++)
      *(short8*)(dp[k]) = cvt8(va[2 * k], va[2 * k + 1]);
    return;
  }

  // ---- gate part ----
  const int lane = threadIdx.x & 63;
  const int wid  = threadIdx.x >> 6;
  const int t    = blockIdx.x * 4 + wid;
  const int e    = lane & 15;
  const int p    = lane >> 4;

  const float* xp = x + (size_t)t * DD + p * 256;
  const float* gp = gw + (size_t)e * DD + p * 256;

  double a0 = 0.0, a1 = 0.0, a2 = 0.0, a3 = 0.0;
  #pragma unroll 8
  for (int i = 0; i < 64; i++) {
    f32x4 xa = *(const f32x4*)(xp + i * 4);
    f32x4 ga = *(const f32x4*)(gp + i * 4);
    a0 += (double)xa[0] * (double)ga[0];
    a1 += (double)xa[1] * (double)ga[1];
    a2 += (double)xa[2] * (double)ga[2];
    a3 += (double)xa[3] * (double)ga[3];
  }
  double acc = (a0 + a1) + (a2 + a3);
  acc += __shfl_xor(acc, 16);
  acc += __shfl_xor(acc, 32);
  float accf = (float)acc;

  float lf[EE], sc[EE], r[EE];
  #pragma unroll
  for (int j = 0; j < EE; j++) lf[j] = __shfl(accf, j);
  #pragma unroll
  for (int j = 0; j < EE; j++) {
    sc[j] = 1.f / (1.f + expf(-lf[j]));
    r[j] = sc[j] + gb[j];
  }
  float gs[4];
  #pragma unroll
  for (int g = 0; g < 4; g++) {
    float m1 = -1e30f, m2 = -1e30f;
    #pragma unroll
    for (int j = 0; j < 4; j++) {
      float v = r[g * 4 + j];
      if (v > m1) { m2 = m1; m1 = v; }
      else if (v > m2) { m2 = v; }
    }
    gs[g] = m1 + m2;
  }
  int g1 = 0, g2 = -1; float b1 = -1e30f, b2 = -1e30f;
  #pragma unroll
  for (int g = 0; g < 4; g++) {
    if (gs[g] > b1) { b2 = b1; g2 = g1; b1 = gs[g]; g1 = g; }
    else if (gs[g] > b2) { b2 = gs[g]; g2 = g; }
  }
  int idx[4]; float wv[4]; float wsum = 0.f;
  unsigned used = 0;
  #pragma unroll
  for (int k = 0; k < 4; k++) {
    float best = -1e30f; int bi = 0;
    #pragma unroll
    for (int j = 0; j < EE; j++) {
      int g = j >> 2;
      bool keep = (g == g1) || (g == g2);
      if (keep && !((used >> j) & 1) && r[j] > best) { best = r[j]; bi = j; }
    }
    used |= 1u << bi; idx[k] = bi; wv[k] = sc[bi]; wsum += sc[bi];
  }
  float div = wsum < 1e-9f ? 1e-9f : wsum;
  if (lane < 4) {
    float w = wv[lane] / div * 2.5446f;
    int slot = atomicAdd(&counts[idx[lane] * CSTR], 1);
    tok[idx[lane] * CAP + slot] = t;
    wgt[idx[lane] * CAP + slot] = w;
    eslot[t * 4 + lane] = (idx[lane] << 16) | slot;
  }
}

// pipeline sync helpers: counted vmcnt + raw barrier (NO full drain)
#define WAIT_PREV_TILE()  do { \
    asm volatile("s_waitcnt vmcnt(8)" ::: "memory"); \
    __builtin_amdgcn_sched_barrier(0); \
    __builtin_amdgcn_s_barrier(); \
    __builtin_amdgcn_sched_barrier(0); } while (0)
#define WAIT_LAST_TILE()  do { \
    asm volatile("s_waitcnt vmcnt(0)" ::: "memory"); \
    __builtin_amdgcn_sched_barrier(0); \
    __builtin_amdgcn_s_barrier(); \
    __builtin_amdgcn_sched_barrier(0); } while (0)
#define END_TILE_BARRIER() do { \
    __builtin_amdgcn_sched_barrier(0); \
    __builtin_amdgcn_s_barrier(); } while (0)

// ---------------- merged GEMM1 + SwiGLU (bf16, dbuf pipeline) ----------------
// grid (11, 16, 19) = 3344 blocks, 256 threads (4 waves).
// Tile M=128, N=64 (dual B: W1,W3), BK=64 -> dbuf LDS = 64KB, 2 blocks/CU.
// 704 = 11*64, 1408 = 22*64: zero N padding. Each wave owns one 16-col strip
// x all 128 rows (acc 64 f32/thread; r2 spill lesson: keep VGPR ~100).
// 2-phase pipeline: STAGE(next) -> vmcnt(8) [waits only CURRENT tile's loads,
// issued one full K-step earlier] -> raw s_barrier -> MFMA -> barrier.
// Expert-clustered XCD swizzle (r1, confirmed -80MB FETCH):
//   F = bx + 11*(by+16*bz); XCD=F&7, rank=F>>3.  ranks: [0,22) w2/ws2 convert,
//   [22,374) routed e=r8+8*((rank-22)/176), [374,418) shared (2 col-planes).
__global__ __launch_bounds__(256, 2)
void gemm1_merged(const short* __restrict__ xb, const short* __restrict__ w1b,
                  const short* __restrict__ w3b, const short* __restrict__ ws1b,
                  const short* __restrict__ ws3b, short* __restrict__ act_r,
                  short* __restrict__ act_s, const int* __restrict__ counts,
                  const int* __restrict__ tok,
                  const float* __restrict__ w2f, const float* __restrict__ ws2f,
                  short* __restrict__ w2bd, short* __restrict__ ws2bd)
{
  const int F = blockIdx.x + 11 * (blockIdx.y + 16 * blockIdx.z);
  const int r8 = F & 7, rank = F >> 3;
  int z, Mt, Ntc;
  if (rank < 22) {                    // convert plane
    z = 0;
    const int p = rank * 8 + r8;
    Mt = p / 11; Ntc = p - Mt * 11;
  } else if (rank < 374) {            // routed experts, clustered per XCD
    const int rr = rank - 22;
    z = 1 + r8 + 8 * (rr / 176);
    const int p = rr % 176;
    Mt = p / 11; Ntc = p - Mt * 11;   // Nt-minor: A-tile stays L2-hot across Nt
  } else {                            // shared FFN, spread across XCDs
    z = 17;
    const int p = (rank - 374) * 8 + r8;
    Mt = p / 22; Ntc = p - Mt * 22;
  }

  if (z == 0) {
    // ---- overlapped convert of w2 + ws2 (only gemm2 needs them) ----
    const int bid = Mt * 11 + Ntc;
    const int tid = threadIdx.x;
    for (int s = 0; s < 9; s++) {
      const size_t base = (size_t)bid * 73728 + (size_t)s * 8192;
      const float* sp[4]; short* dp[4];
      #pragma unroll
      for (int k = 0; k < 4; k++) {
        const size_t sb = base + (size_t)k * 2048;
        if (sb < W2SZ) {
          sp[k] = w2f + sb + tid * 8;
          dp[k] = w2bd + sb + tid * 8;
        } else {
          const size_t o = sb - W2SZ;
          sp[k] = ws2f + o + tid * 8;
          dp[k] = ws2bd + o + tid * 8;
        }
      }
      f32x4 va[8];
      #pragma unroll
      for (int k = 0; k < 4; k++) {
        va[2 * k]     = *(const f32x4*)(sp[k]);
        va[2 * k + 1] = *(const f32x4*)(sp[k] + 4);
      }
      #pragma unroll
      for (int k = 0; k < 4; k++)
        *(short8*)(dp[k]) = cvt8(va[2 * k], va[2 * k + 1]);
    }
    return;
  }

  const bool routed = (z <= EE);
  const int e = z - 1;

  int cnt, N, rowbase = 0;
  const short *W1, *W3;
  short* act;
  if (routed) {
    cnt = counts[e * CSTR];
    if (Mt * 128 >= cnt) return;
    int rb = 0;
    for (int i = 0; i < e; i++) rb += counts[i * CSTR];
    rowbase = rb;
    N = HH;
    W1 = w1b + (size_t)e * HH * DD;
    W3 = w3b + (size_t)e * HH * DD;
    act = act_r;
  } else {
    cnt = TT; N = HSS; W1 = ws1b; W3 = ws3b; act = act_s;
  }
  const int NtB = Ntc * 64;

  __shared__ __align__(16) short lA [2][128 * 64];
  __shared__ __align__(16) short lB1[2][64 * 64];
  __shared__ __align__(16) short lB3[2][64 * 64];

  const int tid = threadIdx.x, lane = tid & 63, wv = tid >> 6;   // wv 0..3
  const int srow = lane >> 3, schunk = lane & 7, scg = schunk ^ srow;

  const short* pa[4]; const short* pb1[2]; const short* pb3[2];
  #pragma unroll
  for (int i = 0; i < 4; i++) {
    const int g = wv * 4 + i;                 // 16 row-groups of 8
    int arow = Mt * 128 + g * 8 + srow;
    if (routed) {
      int slot = arow < cnt ? arow : cnt - 1;
      arow = tok[e * CAP + slot];
    }
    pa[i] = xb + (size_t)arow * DD + scg * 8;
  }
  #pragma unroll
  for (int i = 0; i < 2; i++) {
    const int g = wv * 2 + i;                 // 8 B row-groups of 8
    const int brow = NtB + g * 8 + srow;      // <= N-1 always (exact tiling)
    pb1[i] = W1 + (size_t)brow * DD + scg * 8;
    pb3[i] = W3 + (size_t)brow * DD + scg * 8;
  }

  f32x4 acc1[8], acc3[8];
  #pragma unroll
  for (int i = 0; i < 8; i++) { acc1[i] = (f32x4)0.f; acc3[i] = (f32x4)0.f; }

  const int q = lane >> 4, r7 = lane & 7, hi = (lane & 15) >> 3;

#define STAGE1(c, kk) do { \
    _Pragma("unroll") for (int i = 0; i < 4; i++) \
      ldsload16(pa[i] + (kk),  &lA [c][(wv * 4 + i) * 512]); \
    _Pragma("unroll") for (int i = 0; i < 2; i++) { \
      ldsload16(pb1[i] + (kk), &lB1[c][(wv * 2 + i) * 512]); \
      ldsload16(pb3[i] + (kk), &lB3[c][(wv * 2 + i) * 512]); } } while (0)

#define GEMM1_BODY(c) do { \
    _Pragma("unroll") for (int kc = 0; kc < 2; kc++) { \
      const int cx = (kc * 4 + q) ^ r7; \
      SB8 b1f, b3f; \
      b1f.s = *(const short8*)(&lB1[c][((wv * 2 + hi) * 64 + r7 * 8 + cx) * 8]); \
      b3f.s = *(const short8*)(&lB3[c][((wv * 2 + hi) * 64 + r7 * 8 + cx) * 8]); \
      _Pragma("unroll") for (int mt = 0; mt < 8; mt++) { \
        SB8 af; af.s = *(const short8*)(&lA[c][((2 * mt + hi) * 64 + r7 * 8 + cx) * 8]); \
        acc1[mt] = __builtin_amdgcn_mfma_f32_16x16x32_bf16(af.b, b1f.b, acc1[mt], 0, 0, 0); \
        acc3[mt] = __builtin_amdgcn_mfma_f32_16x16x32_bf16(af.b, b3f.b, acc3[mt], 0, 0, 0); \
      } } } while (0)

  STAGE1(0, 0);
  int cur = 0;
  for (int kk = 64; kk < DD; kk += 64) {
    STAGE1(cur ^ 1, kk);
    WAIT_PREV_TILE();
    GEMM1_BODY(cur);
    END_TILE_BARRIER();
    cur ^= 1;
  }
  WAIT_LAST_TILE();
  GEMM1_BODY(cur);

  const int quad = lane >> 4, lcol = lane & 15;
  const int col = NtB + wv * 16 + lcol;       // < N always
  #pragma unroll
  for (int mt = 0; mt < 8; mt++) {
    #pragma unroll
    for (int rg = 0; rg < 4; rg++) {
      const int r = Mt * 128 + mt * 16 + quad * 4 + rg;
      if (r < cnt) {
        float g = acc1[mt][rg], u = acc3[mt][rg];
        float a = g / (1.f + __expf(-g)) * u;
        act[(size_t)(rowbase + r) * N + col] = f2bf(a);
      }
    }
  }
#undef STAGE1
#undef GEMM1_BODY
}

// ---------------- merged GEMM2 (down proj, bf16, dbuf pipeline) ----------------
// grid (8, 16, 17) = 2176, 256 threads, tile 128x128 BK=64, dbuf LDS 64KB.
// Clean pipeline isolate: tile/indexing identical to r3, only staging pipelined.
__global__ __launch_bounds__(256, 2)
void gemm2_merged(const short* __restrict__ act_r, const short* __restrict__ act_s,
                  const short* __restrict__ w2b, const short* __restrict__ ws2b,
                  float* __restrict__ y, float* __restrict__ outr,
                  const int* __restrict__ counts, const float* __restrict__ wgt)
{
  const int F = blockIdx.x + 8 * (blockIdx.y + 16 * blockIdx.z);
  const int r8 = F & 7, rank = F >> 3;
  int z, Mt, Nt;
  if (rank < 256) {
    z = r8 + 8 * (rank >> 7);
    const int p = rank & 127;
    Mt = p >> 3; Nt = p & 7;
  } else {
    z = 16;
    const int p = (rank - 256) * 8 + r8;
    Mt = p >> 3; Nt = p & 7;
  }

  const bool routed = (z < EE);

  int cnt, Kd, rowbase = 0;
  const short *A, *W;
  if (routed) {
    cnt = counts[z * CSTR];
    if (Mt * 128 >= cnt) return;
    int rb = 0;
    for (int i = 0; i < z; i++) rb += counts[i * CSTR];
    rowbase = rb;
    Kd = HH;
    A = act_r + (size_t)rowbase * HH;
    W = w2b + (size_t)z * DD * HH;
  } else {
    cnt = TT; Kd = HSS; A = act_s; W = ws2b;
  }

  __shared__ __align__(16) short lA[2][128 * 64];
  __shared__ __align__(16) short lB[2][128 * 64];

  const int tid = threadIdx.x, lane = tid & 63, wv = tid >> 6;
  const int srow = lane >> 3, schunk = lane & 7, scg = schunk ^ srow;

  const short* pa[4]; const short* pb[4];
  #pragma unroll
  for (int i = 0; i < 4; i++) {
    const int g = wv * 4 + i;
    int arow = Mt * 128 + g * 8 + srow;
    if (arow >= cnt) arow = cnt - 1;
    pa[i] = A + (size_t)arow * Kd + scg * 8;
    const int brow = Nt * 128 + g * 8 + srow;   // <= 1023 always
    pb[i] = W + (size_t)brow * Kd + scg * 8;
  }

  f32x4 acc[8][2];
  #pragma unroll
  for (int i = 0; i < 8; i++) { acc[i][0] = (f32x4)0.f; acc[i][1] = (f32x4)0.f; }

  const int q = lane >> 4, r7 = lane & 7, hi = (lane & 15) >> 3;

#define STAGE2(c, kk) do { \
    _Pragma("unroll") for (int i = 0; i < 4; i++) { \
      const int g = wv * 4 + i; \
      ldsload16(pa[i] + (kk), &lA[c][g * 512]); \
      ldsload16(pb[i] + (kk), &lB[c][g * 512]); } } while (0)

#define GEMM2_BODY(c) do { \
    _Pragma("unroll") for (int kc = 0; kc < 2; kc++) { \
      const int cx = (kc * 4 + q) ^ r7; \
      SB8 bf[2]; \
      _Pragma("unroll") for (int ntl = 0; ntl < 2; ntl++) { \
        const int a16 = ((wv * 2 + ntl) * 2 + hi) * 64 + r7 * 8 + cx; \
        bf[ntl].s = *(const short8*)(&lB[c][a16 * 8]); \
      } \
      _Pragma("unroll") for (int mt = 0; mt < 8; mt++) { \
        const int a16 = (2 * mt + hi) * 64 + r7 * 8 + cx; \
        SB8 af; af.s = *(const short8*)(&lA[c][a16 * 8]); \
        acc[mt][0] = __builtin_amdgcn_mfma_f32_16x16x32_bf16(af.b, bf[0].b, acc[mt][0], 0, 0, 0); \
        acc[mt][1] = __builtin_amdgcn_mfma_f32_16x16x32_bf16(af.b, bf[1].b, acc[mt][1], 0, 0, 0); \
      } } } while (0)

  STAGE2(0, 0);
  int cur = 0;
  for (int kk = 64; kk < Kd; kk += 64) {
    STAGE2(cur ^ 1, kk);
    WAIT_PREV_TILE();
    GEMM2_BODY(cur);
    END_TILE_BARRIER();
    cur ^= 1;
  }
  WAIT_LAST_TILE();
  GEMM2_BODY(cur);

  const int quad = lane >> 4, lcol = lane & 15;
  #pragma unroll
  for (int mt = 0; mt < 8; mt++) {
    #pragma unroll
    for (int ntl = 0; ntl < 2; ntl++) {
      const int col = Nt * 128 + (wv * 2 + ntl) * 16 + lcol;
      #pragma unroll
      for (int rg = 0; rg < 4; rg++) {
        const int slot = Mt * 128 + mt * 16 + quad * 4 + rg;
        const float v = acc[mt][ntl][rg];
        if (routed) {
          if (slot < cnt) {
            const float w = wgt[z * CAP + slot];
            outr[(size_t)(rowbase + slot) * DD + col] = w * v;
          }
        } else {
          y[(size_t)slot * DD + col] = v;
        }
      }
    }
  }
#undef STAGE2
#undef GEMM2_BODY
}

// ---------------- combine: y[t] += sum_k outr[offs[e_k]+slot_k] ----------------
__global__ __launch_bounds__(256)
void combine_kernel(float* __restrict__ y, const float* __restrict__ outr,
                    const int* __restrict__ eslot, const int* __restrict__ counts)
{
  const int t = blockIdx.x;
  const int d = threadIdx.x * 4;

  int offs[EE];
  int s = 0;
  #pragma unroll
  for (int i = 0; i < EE; i++) { offs[i] = s; s += counts[i * CSTR]; }

  f32x4 accv = *(f32x4*)(y + (size_t)t * DD + d);
  #pragma unroll
  for (int k = 0; k < 4; k++) {
    const int es = eslot[t * 4 + k];
    const int row = offs[es >> 16] + (es & 0xFFFF);
    accv += *(const f32x4*)(outr + (size_t)row * DD + d);
  }
  *(f32x4*)(y + (size_t)t * DD + d) = accv;
}

// ---------------- launch ----------------
extern "C" void kernel_launch(void* const* d_in, const int* in_sizes, int n_in,
                              void* d_out, int out_size, void* d_ws, size_t ws_size,
                              hipStream_t stream) {
  const float* x      = (const float*)d_in[0];
  const float* gate_w = (const float*)d_in[1];
  const float* gate_b = (const float*)d_in[2];
  const float* w1     = (const float*)d_in[3];
  const float* w3     = (const float*)d_in[4];
  const float* w2     = (const float*)d_in[5];
  const float* ws1    = (const float*)d_in[6];
  const float* ws3    = (const float*)d_in[7];
  const float* ws2    = (const float*)d_in[8];
  float* y = (float*)d_out;

  char* ws = (char*)d_ws;
  // layout: counts@0 (2KB, 128B-strided), tok@2048 (128KB), wgt (128KB),
  //         eslot (32KB), bf16 area, act_r, act_s.  Total ~100 MB.
  int*   counts = (int*)ws;
  int*   tok    = (int*)(ws + 2048);
  float* wgt    = (float*)(ws + 2048 + (size_t)EE * CAP * 4);
  int*   eslot  = (int*)(ws + 2048 + (size_t)EE * CAP * 8);
  short* bf     = (short*)(ws + 2048 + (size_t)EE * CAP * 8 + (size_t)TT * 16);
  short* xb   = bf;
  short* w1b  = bf + O1;
  short* w3b  = bf + O2;
  short* w2b  = bf + O3;
  short* ws1b = bf + O4;
  short* ws3b = bf + O5;
  short* ws2b = bf + O6;
  short* act_r = bf + CVT_TOTAL;                 // [8192][704] bf16
  short* act_s = act_r + (size_t)8192 * HH;      // [2048][1408] bf16
  // outr (fp32 [8192][1024], 33.5 MB) aliases w1b/w3b (46 MB, dead after gemm1)
  float* outr = (float*)(bf + O1);

  (void)hipMemsetAsync(counts, 0, EE * CSTR * sizeof(int), stream);

  gate_cvt<<<GATE_BLOCKS + CVTA_BLOCKS, 256, 0, stream>>>(
      x, w1, w3, ws1, ws3, bf,
      gate_w, gate_b, counts, tok, wgt, eslot);

  gemm1_merged<<<dim3(11, TT / 128, EE + 3), 256, 0, stream>>>(
      xb, w1b, w3b, ws1b, ws3b, act_r, act_s, counts, tok,
      w2, ws2, w2b, ws2b);

  gemm2_merged<<<dim3(DD / 128, TT / 128, EE + 1), 256, 0, stream>>>(
      act_r, act_s, w2b, ws2b, y, outr, counts, wgt);

  combine_kernel<<<TT, 256, 0, stream>>>(y, outr, eslot, counts);
}

// Round 6
// 300.584 us; speedup vs baseline: 1.0528x; 1.0528x over previous
//
#include <hip/hip_runtime.h>
#include <hip/hip_bf16.h>
#include <math.h>

// ---------------- types ----------------
typedef __attribute__((ext_vector_type(4))) float   f32x4;
typedef __attribute__((ext_vector_type(8))) short   short8;
typedef __attribute__((ext_vector_type(8))) __bf16  bf16x8;

union SB8 { short8 s; bf16x8 b; };

__device__ __forceinline__ short f2bf(float f) {
  union { float f; unsigned u; } v; v.f = f;
  unsigned r = v.u + 0x7fffu + ((v.u >> 16) & 1u);   // RNE
  return (short)(r >> 16);
}

__device__ __forceinline__ short8 cvt8(f32x4 a, f32x4 b) {
  short8 r;
  r[0] = f2bf(a[0]); r[1] = f2bf(a[1]); r[2] = f2bf(a[2]); r[3] = f2bf(a[3]);
  r[4] = f2bf(b[0]); r[5] = f2bf(b[1]); r[6] = f2bf(b[2]); r[7] = f2bf(b[3]);
  return r;
}

// async global->LDS, 16B per lane; dest is wave-uniform base + lane*16
__device__ __forceinline__ void ldsload16(const short* g, short* l) {
  __builtin_amdgcn_global_load_lds(
      (const __attribute__((address_space(1))) unsigned int*)g,
      (__attribute__((address_space(3))) unsigned int*)l, 16, 0, 0);
}

// Problem constants
#define TT   2048
#define DD   1024        // K of gemm1, N of gemm2
#define HH   704
#define HSS  1408
#define EE   16
#define CAP  2048
#define CSTR 32          // counts stride in ints (128B apart -> no atomic line contention)

// bf16 segment offsets (elements) inside the big bf16 workspace buffer
#define O1  2097152ULL                    // x:  2048*1024
#define O2  13631488ULL                   // w1: 16*704*1024
#define O3  25165824ULL                   // w3
#define O4  36700160ULL                   // w2: 16*1024*704
#define O5  38141952ULL                   // ws1: 1408*1024
#define O6  39583744ULL                   // ws3
#define CVT_TOTAL 41025536ULL             // + ws2

#define W2SZ    11534336ULL               // w2 elems
#define WS1SZ   1441792ULL                // ws1 elems
#define WS1END  26607616ULL               // O3 + WS1SZ
#define CVTA_TOTAL  28049408ULL           // x + w1 + w3 + ws1 + ws3
#define CVTA_BLOCKS 3424                  // CVTA_TOTAL / 8192
#define GATE_BLOCKS 512

// ---------------- fused gate + fp32->bf16 convert (unchanged from r3) ----------------
__global__ __launch_bounds__(256)
void gate_cvt(const float* __restrict__ x,  const float* __restrict__ w1,
              const float* __restrict__ w3, const float* __restrict__ s1,
              const float* __restrict__ s3, short* __restrict__ dst,
              const float* __restrict__ gw, const float* __restrict__ gb,
              int* __restrict__ counts, int* __restrict__ tok,
              float* __restrict__ wgt, int* __restrict__ eslot)
{
  if (blockIdx.x >= GATE_BLOCKS) {
    const int tid = threadIdx.x;
    const size_t base = (size_t)(blockIdx.x - GATE_BLOCKS) * 8192;
    const float* sp[4]; short* dp[4];
    #pragma unroll
    for (int k = 0; k < 4; k++) {
      const size_t sb = base + (size_t)k * 2048;          // uniform per (block,k)
      const float* src; size_t doff;
      if      (sb < O1)     { src = x  + sb;            doff = sb; }
      else if (sb < O2)     { src = w1 + (sb - O1);     doff = sb; }
      else if (sb < O3)     { src = w3 + (sb - O2);     doff = sb; }
      else if (sb < WS1END) { src = s1 + (sb - O3);     doff = sb + W2SZ; }
      else                  { src = s3 + (sb - WS1END); doff = sb + W2SZ; }
      sp[k] = src + tid * 8;
      dp[k] = dst + doff + tid * 8;
    }
    f32x4 va[8];
    #pragma unroll
    for (int k = 0; k < 4; k++) {
      va[2 * k]     = *(const f32x4*)(sp[k]);
      va[2 * k + 1] = *(const f32x4*)(sp[k] + 4);
    }
    #pragma unroll
    for (int k = 0; k < 4; k++)
      *(short8*)(dp[k]) = cvt8(va[2 * k], va[2 * k + 1]);
    return;
  }

  // ---- gate part ----
  const int lane = threadIdx.x & 63;
  const int wid  = threadIdx.x >> 6;
  const int t    = blockIdx.x * 4 + wid;
  const int e    = lane & 15;
  const int p    = lane >> 4;

  const float* xp = x + (size_t)t * DD + p * 256;
  const float* gp = gw + (size_t)e * DD + p * 256;

  double a0 = 0.0, a1 = 0.0, a2 = 0.0, a3 = 0.0;
  #pragma unroll 8
  for (int i = 0; i < 64; i++) {
    f32x4 xa = *(const f32x4*)(xp + i * 4);
    f32x4 ga = *(const f32x4*)(gp + i * 4);
    a0 += (double)xa[0] * (double)ga[0];
    a1 += (double)xa[1] * (double)ga[1];
    a2 += (double)xa[2] * (double)ga[2];
    a3 += (double)xa[3] * (double)ga[3];
  }
  double acc = (a0 + a1) + (a2 + a3);
  acc += __shfl_xor(acc, 16);
  acc += __shfl_xor(acc, 32);
  float accf = (float)acc;

  float lf[EE], sc[EE], r[EE];
  #pragma unroll
  for (int j = 0; j < EE; j++) lf[j] = __shfl(accf, j);
  #pragma unroll
  for (int j = 0; j < EE; j++) {
    sc[j] = 1.f / (1.f + expf(-lf[j]));
    r[j] = sc[j] + gb[j];
  }
  float gs[4];
  #pragma unroll
  for (int g = 0; g < 4; g++) {
    float m1 = -1e30f, m2 = -1e30f;
    #pragma unroll
    for (int j = 0; j < 4; j++) {
      float v = r[g * 4 + j];
      if (v > m1) { m2 = m1; m1 = v; }
      else if (v > m2) { m2 = v; }
    }
    gs[g] = m1 + m2;
  }
  int g1 = 0, g2 = -1; float b1 = -1e30f, b2 = -1e30f;
  #pragma unroll
  for (int g = 0; g < 4; g++) {
    if (gs[g] > b1) { b2 = b1; g2 = g1; b1 = gs[g]; g1 = g; }
    else if (gs[g] > b2) { b2 = gs[g]; g2 = g; }
  }
  int idx[4]; float wv[4]; float wsum = 0.f;
  unsigned used = 0;
  #pragma unroll
  for (int k = 0; k < 4; k++) {
    float best = -1e30f; int bi = 0;
    #pragma unroll
    for (int j = 0; j < EE; j++) {
      int g = j >> 2;
      bool keep = (g == g1) || (g == g2);
      if (keep && !((used >> j) & 1) && r[j] > best) { best = r[j]; bi = j; }
    }
    used |= 1u << bi; idx[k] = bi; wv[k] = sc[bi]; wsum += sc[bi];
  }
  float div = wsum < 1e-9f ? 1e-9f : wsum;
  if (lane < 4) {
    float w = wv[lane] / div * 2.5446f;
    int slot = atomicAdd(&counts[idx[lane] * CSTR], 1);
    tok[idx[lane] * CAP + slot] = t;
    wgt[idx[lane] * CAP + slot] = w;
    eslot[t * 4 + lane] = (idx[lane] << 16) | slot;
  }
}

// pipeline sync helpers: counted vmcnt + raw barrier (NO full drain).
// sched_barrier(0) after s_barrier keeps the compiler from hoisting LDS reads
// above the barrier (raw s_barrier has no compiler-visible ordering).
#define WAIT_PREV_TILE()  do { \
    asm volatile("s_waitcnt vmcnt(4)" ::: "memory"); \
    __builtin_amdgcn_sched_barrier(0); \
    __builtin_amdgcn_s_barrier(); \
    __builtin_amdgcn_sched_barrier(0); } while (0)
#define WAIT_LAST_TILE()  do { \
    asm volatile("s_waitcnt vmcnt(0)" ::: "memory"); \
    __builtin_amdgcn_sched_barrier(0); \
    __builtin_amdgcn_s_barrier(); \
    __builtin_amdgcn_sched_barrier(0); } while (0)
#define END_TILE_BARRIER() do { \
    __builtin_amdgcn_sched_barrier(0); \
    __builtin_amdgcn_s_barrier(); } while (0)

// ---------------- merged GEMM1 + SwiGLU (bf16, 8-wave dbuf pipeline) ----------------
// grid (11, 16, 19) = 3344 blocks, 512 threads (8 waves).
// Tile M=128, N=64 (dual B: W1,W3), BK=64, dbuf LDS 64KB -> 2 blocks/CU,
// 16 waves/CU = 4 waves/SIMD (r3: 3, r5: 2).  Wave (mh=wv>>2, wc=wv&3) owns
// rows [mh*64,+64) x cols [wc*16,+16): acc 32 f32/thread, VGPR ~72.
// Counted vmcnt(4): stage issues 4 loads/thread; the wait covers only the
// PREVIOUS tile's loads (issued one full MFMA body earlier) -> no drain stall.
// Expert-clustered XCD swizzle (r1, confirmed) + Nt-minor (r5: FETCH 123->97MB).
__global__ __launch_bounds__(512, 2)
void gemm1_merged(const short* __restrict__ xb, const short* __restrict__ w1b,
                  const short* __restrict__ w3b, const short* __restrict__ ws1b,
                  const short* __restrict__ ws3b, short* __restrict__ act_r,
                  short* __restrict__ act_s, const int* __restrict__ counts,
                  const int* __restrict__ tok,
                  const float* __restrict__ w2f, const float* __restrict__ ws2f,
                  short* __restrict__ w2bd, short* __restrict__ ws2bd)
{
  const int F = blockIdx.x + 11 * (blockIdx.y + 16 * blockIdx.z);
  const int r8 = F & 7, rank = F >> 3;
  int z, Mt, Ntc;
  if (rank < 22) {                    // convert plane
    z = 0;
    const int p = rank * 8 + r8;
    Mt = p / 11; Ntc = p - Mt * 11;
  } else if (rank < 374) {            // routed experts, clustered per XCD
    const int rr = rank - 22;
    z = 1 + r8 + 8 * (rr / 176);
    const int p = rr % 176;
    Mt = p / 11; Ntc = p - Mt * 11;   // Nt-minor: A-tile stays L2-hot across Nt
  } else {                            // shared FFN, spread across XCDs
    z = 17;
    const int p = (rank - 374) * 8 + r8;
    Mt = p / 22; Ntc = p - Mt * 22;
  }

  if (z == 0) {
    // ---- overlapped convert of w2 + ws2 (only gemm2 needs them) ----
    // 512 threads: 3 iters x 6 slabs x 4096 elems = 73728 elems/block.
    const int bid = Mt * 11 + Ntc;
    const int tid = threadIdx.x;
    for (int s = 0; s < 3; s++) {
      const size_t base = (size_t)bid * 73728 + (size_t)s * 24576;
      const float* sp[6]; short* dp[6];
      #pragma unroll
      for (int k = 0; k < 6; k++) {
        const size_t sb = base + (size_t)k * 4096;
        if (sb < W2SZ) {
          sp[k] = w2f + sb + tid * 8;
          dp[k] = w2bd + sb + tid * 8;
        } else {
          const size_t o = sb - W2SZ;
          sp[k] = ws2f + o + tid * 8;
          dp[k] = ws2bd + o + tid * 8;
        }
      }
      f32x4 va[12];
      #pragma unroll
      for (int k = 0; k < 6; k++) {
        va[2 * k]     = *(const f32x4*)(sp[k]);
        va[2 * k + 1] = *(const f32x4*)(sp[k] + 4);
      }
      #pragma unroll
      for (int k = 0; k < 6; k++)
        *(short8*)(dp[k]) = cvt8(va[2 * k], va[2 * k + 1]);
    }
    return;
  }

  const bool routed = (z <= EE);
  const int e = z - 1;

  int cnt, N, rowbase = 0;
  const short *W1, *W3;
  short* act;
  if (routed) {
    cnt = counts[e * CSTR];
    if (Mt * 128 >= cnt) return;
    int rb = 0;
    for (int i = 0; i < e; i++) rb += counts[i * CSTR];
    rowbase = rb;
    N = HH;
    W1 = w1b + (size_t)e * HH * DD;
    W3 = w3b + (size_t)e * HH * DD;
    act = act_r;
  } else {
    cnt = TT; N = HSS; W1 = ws1b; W3 = ws3b; act = act_s;
  }
  const int NtB = Ntc * 64;

  __shared__ __align__(16) short lA [2][128 * 64];
  __shared__ __align__(16) short lB1[2][64 * 64];
  __shared__ __align__(16) short lB3[2][64 * 64];

  const int tid = threadIdx.x, lane = tid & 63, wv = tid >> 6;   // wv 0..7
  const int srow = lane >> 3, schunk = lane & 7, scg = schunk ^ srow;

  const short* pa[2]; const short* pb1; const short* pb3;
  #pragma unroll
  for (int i = 0; i < 2; i++) {
    const int g = wv * 2 + i;                 // 16 A row-groups of 8
    int arow = Mt * 128 + g * 8 + srow;
    if (routed) {
      int slot = arow < cnt ? arow : cnt - 1;
      arow = tok[e * CAP + slot];
    }
    pa[i] = xb + (size_t)arow * DD + scg * 8;
  }
  {
    const int brow = NtB + wv * 8 + srow;     // 8 B row-groups of 8, <= N-1
    pb1 = W1 + (size_t)brow * DD + scg * 8;
    pb3 = W3 + (size_t)brow * DD + scg * 8;
  }

  f32x4 acc1[4], acc3[4];
  #pragma unroll
  for (int i = 0; i < 4; i++) { acc1[i] = (f32x4)0.f; acc3[i] = (f32x4)0.f; }

  const int q = lane >> 4, r7 = lane & 7, hi = (lane & 15) >> 3;
  const int wc = wv & 3, mh = wv >> 2;

#define STAGE1(c, kk) do { \
    ldsload16(pa[0] + (kk), &lA [c][(wv * 2 + 0) * 512]); \
    ldsload16(pa[1] + (kk), &lA [c][(wv * 2 + 1) * 512]); \
    ldsload16(pb1  + (kk),  &lB1[c][wv * 512]); \
    ldsload16(pb3  + (kk),  &lB3[c][wv * 512]); } while (0)

#define GEMM1_BODY(c) do { \
    _Pragma("unroll") for (int kc = 0; kc < 2; kc++) { \
      const int cx = (kc * 4 + q) ^ r7; \
      SB8 b1f, b3f; \
      b1f.s = *(const short8*)(&lB1[c][((wc * 2 + hi) * 64 + r7 * 8 + cx) * 8]); \
      b3f.s = *(const short8*)(&lB3[c][((wc * 2 + hi) * 64 + r7 * 8 + cx) * 8]); \
      _Pragma("unroll") for (int mt = 0; mt < 4; mt++) { \
        SB8 af; af.s = *(const short8*)(&lA[c][((2 * (mh * 4 + mt) + hi) * 64 + r7 * 8 + cx) * 8]); \
        acc1[mt] = __builtin_amdgcn_mfma_f32_16x16x32_bf16(af.b, b1f.b, acc1[mt], 0, 0, 0); \
        acc3[mt] = __builtin_amdgcn_mfma_f32_16x16x32_bf16(af.b, b3f.b, acc3[mt], 0, 0, 0); \
      } } } while (0)

  STAGE1(0, 0);
  int cur = 0;
  for (int kk = 64; kk < DD; kk += 64) {
    STAGE1(cur ^ 1, kk);
    WAIT_PREV_TILE();
    GEMM1_BODY(cur);
    END_TILE_BARRIER();
    cur ^= 1;
  }
  WAIT_LAST_TILE();
  GEMM1_BODY(cur);

  const int quad = lane >> 4, lcol = lane & 15;
  const int col = NtB + wc * 16 + lcol;       // < N always
  #pragma unroll
  for (int mt = 0; mt < 4; mt++) {
    #pragma unroll
    for (int rg = 0; rg < 4; rg++) {
      const int r = Mt * 128 + (mh * 4 + mt) * 16 + quad * 4 + rg;
      if (r < cnt) {
        float g = acc1[mt][rg], u = acc3[mt][rg];
        float a = g / (1.f + __expf(-g)) * u;
        act[(size_t)(rowbase + r) * N + col] = f2bf(a);
      }
    }
  }
#undef STAGE1
#undef GEMM1_BODY
}

// ---------------- merged GEMM2 (down proj, bf16, 8-wave dbuf pipeline) ----------------
// grid (8, 16, 17) = 2176, 512 threads, tile 128x128, BK=64, dbuf LDS 64KB.
// Wave (mh, wc) owns rows [mh*64,+64) x cols [wc*32,+32): acc 32 f32/thread.
__global__ __launch_bounds__(512, 2)
void gemm2_merged(const short* __restrict__ act_r, const short* __restrict__ act_s,
                  const short* __restrict__ w2b, const short* __restrict__ ws2b,
                  float* __restrict__ y, float* __restrict__ outr,
                  const int* __restrict__ counts, const float* __restrict__ wgt)
{
  const int F = blockIdx.x + 8 * (blockIdx.y + 16 * blockIdx.z);
  const int r8 = F & 7, rank = F >> 3;
  int z, Mt, Nt;
  if (rank < 256) {
    z = r8 + 8 * (rank >> 7);
    const int p = rank & 127;
    Mt = p >> 3; Nt = p & 7;
  } else {
    z = 16;
    const int p = (rank - 256) * 8 + r8;
    Mt = p >> 3; Nt = p & 7;
  }

  const bool routed = (z < EE);

  int cnt, Kd, rowbase = 0;
  const short *A, *W;
  if (routed) {
    cnt = counts[z * CSTR];
    if (Mt * 128 >= cnt) return;
    int rb = 0;
    for (int i = 0; i < z; i++) rb += counts[i * CSTR];
    rowbase = rb;
    Kd = HH;
    A = act_r + (size_t)rowbase * HH;
    W = w2b + (size_t)z * DD * HH;
  } else {
    cnt = TT; Kd = HSS; A = act_s; W = ws2b;
  }

  __shared__ __align__(16) short lA[2][128 * 64];
  __shared__ __align__(16) short lB[2][128 * 64];

  const int tid = threadIdx.x, lane = tid & 63, wv = tid >> 6;   // wv 0..7
  const int srow = lane >> 3, schunk = lane & 7, scg = schunk ^ srow;

  const short* pa[2]; const short* pb[2];
  #pragma unroll
  for (int i = 0; i < 2; i++) {
    const int g = wv * 2 + i;
    int arow = Mt * 128 + g * 8 + srow;
    if (arow >= cnt) arow = cnt - 1;
    pa[i] = A + (size_t)arow * Kd + scg * 8;
    const int brow = Nt * 128 + g * 8 + srow;   // <= 1023 always
    pb[i] = W + (size_t)brow * Kd + scg * 8;
  }

  f32x4 acc[4][2];
  #pragma unroll
  for (int i = 0; i < 4; i++) { acc[i][0] = (f32x4)0.f; acc[i][1] = (f32x4)0.f; }

  const int q = lane >> 4, r7 = lane & 7, hi = (lane & 15) >> 3;
  const int wc = wv & 3, mh = wv >> 2;

#define STAGE2(c, kk) do { \
    ldsload16(pa[0] + (kk), &lA[c][(wv * 2 + 0) * 512]); \
    ldsload16(pa[1] + (kk), &lA[c][(wv * 2 + 1) * 512]); \
    ldsload16(pb[0] + (kk), &lB[c][(wv * 2 + 0) * 512]); \
    ldsload16(pb[1] + (kk), &lB[c][(wv * 2 + 1) * 512]); } while (0)

#define GEMM2_BODY(c) do { \
    _Pragma("unroll") for (int kc = 0; kc < 2; kc++) { \
      const int cx = (kc * 4 + q) ^ r7; \
      SB8 bf[2]; \
      _Pragma("unroll") for (int ntl = 0; ntl < 2; ntl++) { \
        const int a16 = ((wc * 2 + ntl) * 2 + hi) * 64 + r7 * 8 + cx; \
        bf[ntl].s = *(const short8*)(&lB[c][a16 * 8]); \
      } \
      _Pragma("unroll") for (int mt = 0; mt < 4; mt++) { \
        const int a16 = (2 * (mh * 4 + mt) + hi) * 64 + r7 * 8 + cx; \
        SB8 af; af.s = *(const short8*)(&lA[c][a16 * 8]); \
        acc[mt][0] = __builtin_amdgcn_mfma_f32_16x16x32_bf16(af.b, bf[0].b, acc[mt][0], 0, 0, 0); \
        acc[mt][1] = __builtin_amdgcn_mfma_f32_16x16x32_bf16(af.b, bf[1].b, acc[mt][1], 0, 0, 0); \
      } } } while (0)

  STAGE2(0, 0);
  int cur = 0;
  for (int kk = 64; kk < Kd; kk += 64) {
    STAGE2(cur ^ 1, kk);
    WAIT_PREV_TILE();
    GEMM2_BODY(cur);
    END_TILE_BARRIER();
    cur ^= 1;
  }
  WAIT_LAST_TILE();
  GEMM2_BODY(cur);

  const int quad = lane >> 4, lcol = lane & 15;
  #pragma unroll
  for (int mt = 0; mt < 4; mt++) {
    #pragma unroll
    for (int ntl = 0; ntl < 2; ntl++) {
      const int col = Nt * 128 + (wc * 2 + ntl) * 16 + lcol;
      #pragma unroll
      for (int rg = 0; rg < 4; rg++) {
        const int slot = Mt * 128 + (mh * 4 + mt) * 16 + quad * 4 + rg;
        const float v = acc[mt][ntl][rg];
        if (routed) {
          if (slot < cnt) {
            const float w = wgt[z * CAP + slot];
            outr[(size_t)(rowbase + slot) * DD + col] = w * v;
          }
        } else {
          y[(size_t)slot * DD + col] = v;
        }
      }
    }
  }
#undef STAGE2
#undef GEMM2_BODY
}

// ---------------- combine: y[t] += sum_k outr[offs[e_k]+slot_k] ----------------
__global__ __launch_bounds__(256)
void combine_kernel(float* __restrict__ y, const float* __restrict__ outr,
                    const int* __restrict__ eslot, const int* __restrict__ counts)
{
  const int t = blockIdx.x;
  const int d = threadIdx.x * 4;

  int offs[EE];
  int s = 0;
  #pragma unroll
  for (int i = 0; i < EE; i++) { offs[i] = s; s += counts[i * CSTR]; }

  f32x4 accv = *(f32x4*)(y + (size_t)t * DD + d);
  #pragma unroll
  for (int k = 0; k < 4; k++) {
    const int es = eslot[t * 4 + k];
    const int row = offs[es >> 16] + (es & 0xFFFF);
    accv += *(const f32x4*)(outr + (size_t)row * DD + d);
  }
  *(f32x4*)(y + (size_t)t * DD + d) = accv;
}

// ---------------- launch ----------------
extern "C" void kernel_launch(void* const* d_in, const int* in_sizes, int n_in,
                              void* d_out, int out_size, void* d_ws, size_t ws_size,
                              hipStream_t stream) {
  const float* x      = (const float*)d_in[0];
  const float* gate_w = (const float*)d_in[1];
  const float* gate_b = (const float*)d_in[2];
  const float* w1     = (const float*)d_in[3];
  const float* w3     = (const float*)d_in[4];
  const float* w2     = (const float*)d_in[5];
  const float* ws1    = (const float*)d_in[6];
  const float* ws3    = (const float*)d_in[7];
  const float* ws2    = (const float*)d_in[8];
  float* y = (float*)d_out;

  char* ws = (char*)d_ws;
  // layout: counts@0 (2KB, 128B-strided), tok@2048 (128KB), wgt (128KB),
  //         eslot (32KB), bf16 area, act_r, act_s.  Total ~100 MB.
  int*   counts = (int*)ws;
  int*   tok    = (int*)(ws + 2048);
  float* wgt    = (float*)(ws + 2048 + (size_t)EE * CAP * 4);
  int*   eslot  = (int*)(ws + 2048 + (size_t)EE * CAP * 8);
  short* bf     = (short*)(ws + 2048 + (size_t)EE * CAP * 8 + (size_t)TT * 16);
  short* xb   = bf;
  short* w1b  = bf + O1;
  short* w3b  = bf + O2;
  short* w2b  = bf + O3;
  short* ws1b = bf + O4;
  short* ws3b = bf + O5;
  short* ws2b = bf + O6;
  short* act_r = bf + CVT_TOTAL;                 // [8192][704] bf16
  short* act_s = act_r + (size_t)8192 * HH;      // [2048][1408] bf16
  // outr (fp32 [8192][1024], 33.5 MB) aliases w1b/w3b (46 MB, dead after gemm1)
  float* outr = (float*)(bf + O1);

  (void)hipMemsetAsync(counts, 0, EE * CSTR * sizeof(int), stream);

  gate_cvt<<<GATE_BLOCKS + CVTA_BLOCKS, 256, 0, stream>>>(
      x, w1, w3, ws1, ws3, bf,
      gate_w, gate_b, counts, tok, wgt, eslot);

  gemm1_merged<<<dim3(11, TT / 128, EE + 3), 512, 0, stream>>>(
      xb, w1b, w3b, ws1b, ws3b, act_r, act_s, counts, tok,
      w2, ws2, w2b, ws2b);

  gemm2_merged<<<dim3(DD / 128, TT / 128, EE + 1), 512, 0, stream>>>(
      act_r, act_s, w2b, ws2b, y, outr, counts, wgt);

  combine_kernel<<<TT, 256, 0, stream>>>(y, outr, eslot, counts);
}